// Round 14
// baseline (46.883 us; speedup 1.0000x reference)
//
#include <hip/hip_runtime.h>
#include <hip/hip_bf16.h>

// ws layout (requires ws_size >= 17039360 B):
//   [0, 221184)        : weights as bf16 in 16x16x32 MFMA B-fragment order
//   [221184, 221440)   : 256 B of zeros (OOB halo source)
//   [262144, 17039360) : x_t = x transposed to [b][s][c] bf16 (16 MiB)
#define WS_W_OFF    0
#define WS_ZERO_OFF 221184
#define WS_XT_OFF   262144

typedef __attribute__((ext_vector_type(8))) short s16x8;
typedef __attribute__((ext_vector_type(4))) float f32x4;

#define GLOBAL_AS __attribute__((address_space(1)))
#define LDS_AS    __attribute__((address_space(3)))

__device__ __forceinline__ unsigned short f2bf(float f) {
  unsigned u = __builtin_bit_cast(unsigned, f);
  u = u + 0x7fffu + ((u >> 16) & 1u);
  return (unsigned short)(u >> 16);
}

// ---------------------------------------------------------------------------
// Fused prep (VERIFIED rounds 5/9/10/12/13, byte-identical): blocks [0,432)
// repack weights into 16x16x32 B-fragments; blocks [432,4528) transpose x.
// Fragment f = (tap*2+h)*4+nf holds B[n][k] for n = nf*16 + (lane&15),
// cin = h*32 + (lane>>4)*8 + j. bf16 index = (f*64 + lane)*8 + j.
// The 4 KB tile for (tap,h) is contiguous at byte offset (tap*2+h)*4096.
__global__ void prep_kernel(const float* __restrict__ x,
                            const float* __restrict__ w,
                            unsigned short* __restrict__ wsw,
                            float* __restrict__ zeros,
                            unsigned short* __restrict__ xt) {
  int blk = blockIdx.x;
  if (blk < 432) {
    int t = blk * 256 + threadIdx.x;             // 110592 threads exactly
    int tap  = t % 27;
    int cin  = (t / 27) & 63;
    int cout = t / (27 * 64);
    int h   = cin >> 5;
    int q   = (cin >> 3) & 3;
    int j   = cin & 7;
    int nf  = cout >> 4;
    int lane = q * 16 + (cout & 15);
    int dst = (((tap * 2 + h) * 4 + nf) * 64 + lane) * 8 + j;
    wsw[dst] = f2bf(w[t]);
    if (t < 64) zeros[t] = 0.0f;
  } else {
    int t  = (blk - 432) * 256 + threadIdx.x;    // 1048576 threads
    int s  = t & 32767;
    int c8 = (t >> 15) & 7;
    int b  = t >> 18;
    const float* src = x + (size_t)(b * 64 + c8 * 8) * 32768 + s;
    s16x8 v;
    #pragma unroll
    for (int k = 0; k < 8; ++k) v[k] = (short)f2bf(src[(size_t)k * 32768]);
    *(s16x8*)(xt + (size_t)(b * 32768 + s) * 64 + c8 * 8) = v;
  }
}

// ---------------------------------------------------------------------------
// Implicit-GEMM conv: M_w = 128, 1 wave/SIMD, deep per-wave ILP (m201 regime).
// Block = (b, z-quad, y-quad): 4z x 4y x 32x = 512 outputs x 64 couts,
// 256 threads = 4 waves, grid 256 = exactly 1 block/CU, ONE generation.
// Wave w owns z-row z0+w ENTIRELY: 4y x 32x = 128 outputs, N_w = 64
// -> acc[8][4] f32x4 = 128 VGPR, reads/MFMA = 12/32 = 0.375.
// Per tap: 12 ds_read_b128 (144 cy issue) + 32 MFMA (620 cy matrix pipe);
// no barriers inside a 9-tap group -> compiler's counted lgkmcnt interleaves
// next-tap reads between MFMAs; read latency hides inside the wave's own
// MFMA stream (no cross-wave phase alternation possible at 1 wave/SIMD).
// Per-CU per tap-half: matrix 620 cy (binding) vs LDS 4x12x12 = 576 cy.
//
// LDS (152064 B): halo 1224 pos x 64 B (LINEAR: pos p at halo[p*64], chunk c
// at +c*16; each ds_read_b128 = 8 dwords/bank = floor) + blds 2 x 36864 B
// (double-buffered 9-tap B group; B-read = 8 dwords/bank = floor).
__global__ __launch_bounds__(256, 1) void conv_kernel(const float* __restrict__ bias,
                                                      float* __restrict__ out,
                                                      const char* __restrict__ ws) {
  __shared__ __align__(16) unsigned char halo[1224 * 64];   // 78336 B
  __shared__ __align__(16) unsigned char blds[2][36864];    // 73728 B

  const int tid  = threadIdx.x;
  const int lane = tid & 63;
  const int w    = tid >> 6;                     // wave 0..3 = z-row
  // XCD swizzle (256 % 8 == 0 -> bijective): 32 contiguous logical blocks
  // per XCD (fixed b, 4 consecutive z-quads) -> x_t slab L2-resident.
  const int logical = (blockIdx.x & 7) * 32 + (blockIdx.x >> 3);
  const int yq = logical & 7, zq = (logical >> 3) & 7, b = logical >> 6;
  const int z0 = zq * 4, y0 = yq * 4;

  const int r15 = lane & 15;
  const int hi4 = lane >> 4;

  // ---- halo staging: 4896 16B chunks, 20 rounds of 256, linear dest ----
  auto stage_halo = [&](int h) {
    #pragma unroll 1
    for (int r = 0; r < 20; ++r) {
      int ci = r * 256 + tid;
      if (ci < 4896) {
        int pos = ci >> 2, ch = ci & 3;
        int hz = pos / 204; int rem = pos - hz * 204;      // 204 = 6*34
        int hy = rem / 34;  int hx = rem - hy * 34;
        int gz = z0 + hz - 1, gy = y0 + hy - 1, gx = hx - 1;
        bool inb = ((unsigned)gz < 32u) & ((unsigned)gy < 32u) &
                   ((unsigned)gx < 32u);
        int s = (gz * 32 + gy) * 32 + gx;
        int src = inb ? (WS_XT_OFF + (b * 32768 + s) * 128 + h * 64 + ch * 16)
                      : WS_ZERO_OFF;
        __builtin_amdgcn_global_load_lds(
            (const GLOBAL_AS void*)(ws + src),
            (LDS_AS void*)(&halo[ci * 16]),
            16, 0, 0);
      }
    }
  };

  // ---- B staging: one kd-group = 9 taps x 4 KB = 2304 chunks, 9 rounds ----
  auto stage_B = [&](int h, int kd, int buf) {
    #pragma unroll 1
    for (int r = 0; r < 9; ++r) {
      int ci = r * 256 + tid;
      {
        int tl = ci >> 8, off = ci & 255;
        int src = WS_W_OFF + ((kd * 9 + tl) * 2 + h) * 4096 + off * 16;
        __builtin_amdgcn_global_load_lds(
            (const GLOBAL_AS void*)(ws + src),
            (LDS_AS void*)(&blds[buf][ci * 16]),
            16, 0, 0);
      }
    }
  };

  f32x4 zero4 = {0.f, 0.f, 0.f, 0.f};
  f32x4 acc[8][4];                               // mf = yy*2+xh; 128 VGPR
  #pragma unroll
  for (int mf = 0; mf < 8; ++mf)
    #pragma unroll
    for (int nf = 0; nf < 4; ++nf) acc[mf][nf] = zero4;

  // ---- 9 taps of one kd-slice, all operands LDS, zero barriers ----
  auto run9 = [&](int kd, int buf) {
    #pragma unroll
    for (int tl = 0; tl < 9; ++tl) {
      const int kh = tl / 3, kw = tl % 3;        // compile-time
      s16x8 Bf[4], Af[8];
      #pragma unroll
      for (int nf = 0; nf < 4; ++nf)
        Bf[nf] = *(const s16x8*)&blds[buf][(tl * 256 + nf * 64 + lane) * 16];
      #pragma unroll
      for (int mf = 0; mf < 8; ++mf) {           // yy = mf>>1, xh = mf&1
        int p = ((w + kd) * 6 + (mf >> 1) + kh) * 34
              + kw + (mf & 1) * 16 + r15;
        Af[mf] = *(const s16x8*)&halo[p * 64 + hi4 * 16];
      }
      __builtin_amdgcn_s_setprio(1);
      #pragma unroll
      for (int mf = 0; mf < 8; ++mf)
        #pragma unroll
        for (int nf = 0; nf < 4; ++nf)
          acc[mf][nf] = __builtin_amdgcn_mfma_f32_16x16x32_bf16(
              Af[mf], Bf[nf], acc[mf][nf], 0, 0, 0);
      __builtin_amdgcn_s_setprio(0);
    }
  };

  // ---- half 0 ----
  stage_halo(0); stage_B(0, 0, 0);
  __syncthreads();                   // halo0 + B(kd0) ready
  stage_B(0, 1, 1);
  run9(0, 0);
  __syncthreads();                   // B(kd1) landed (free drain)
  stage_B(0, 2, 0);                  // buf0 free: kd0 reads done pre-barrier
  run9(1, 1);
  __syncthreads();                   // B(kd2) landed
  run9(2, 0);
  __syncthreads();                   // all halo0/blds reads done

  // ---- half 1 ----
  stage_halo(1); stage_B(1, 0, 1);
  __syncthreads();
  stage_B(1, 1, 0);
  run9(0, 1);
  __syncthreads();
  stage_B(1, 2, 1);
  run9(1, 0);
  __syncthreads();
  run9(2, 1);

  // ---- epilogue (verified 16x16 C/D): full-line coalesced stores ----
  const int z = z0 + w;
  #pragma unroll
  for (int nf = 0; nf < 4; ++nf) {
    int cout = nf * 16 + r15;
    float bv = bias[cout];
    #pragma unroll
    for (int mf = 0; mf < 8; ++mf) {
      int y  = y0 + (mf >> 1);
      int x0 = (mf & 1) * 16 + 4 * hi4;
      float* orow = out + ((size_t)((b * 64 + cout) * 32 + z) * 32 + y) * 32;
      f32x4 v;
      #pragma unroll
      for (int r = 0; r < 4; ++r) v[r] = acc[mf][nf][r] + bv;
      *(f32x4*)&orow[x0] = v;
    }
  }
}

extern "C" void kernel_launch(void* const* d_in, const int* in_sizes, int n_in,
                              void* d_out, int out_size, void* d_ws, size_t ws_size,
                              hipStream_t stream) {
  const float* x    = (const float*)d_in[0];
  const float* wgt  = (const float*)d_in[1];
  const float* bias = (const float*)d_in[2];
  float* out = (float*)d_out;
  char* ws = (char*)d_ws;

  prep_kernel<<<4528, 256, 0, stream>>>(x, wgt,
                                        (unsigned short*)(ws + WS_W_OFF),
                                        (float*)(ws + WS_ZERO_OFF),
                                        (unsigned short*)(ws + WS_XT_OFF));
  conv_kernel<<<256, 256, 0, stream>>>(bias, out, ws);
}